// Round 6
// baseline (431.516 us; speedup 1.0000x reference)
//
#include <hip/hip_runtime.h>
#include <math.h>

// MPN-COV: cov = (X X^T - S S^T/N)/(N-1); sqrt via coupled Newton-Schulz
// (3 iters, trace-normalized, Z0=I shortcut); triu-pack fused into final
// NS epilogue.  B=64, C=256, N=4096.  ws ~= 1 GiB.
// Round 6: un-fused finisher (round-5 fusion was latency-bound, 1 blk/CU);
// gram KS=8 -> 512 blocks = 2 blocks/CU, LDS = X-dbuf only (shfl row sums).

#define B_ 64
#define C_ 256
#define N_ 4096
#define TRI ((C_*(C_+1))/2)
#define MATE (C_*C_)
#define TOTE ((size_t)B_*MATE)
#define KS 8
#define KW (N_/KS)              // 512

typedef __attribute__((ext_vector_type(8))) short bf16x8;
typedef __attribute__((ext_vector_type(4))) short short4v;
typedef __attribute__((ext_vector_type(4))) float f32x4;

__device__ __forceinline__ short f2bf(float f) {        // RNE float->bf16
    unsigned u = __float_as_uint(f);
    return (short)((u + 0x7FFFu + ((u >> 16) & 1u)) >> 16);
}
__device__ __forceinline__ float bf2f(short s) {
    return __uint_as_float(((unsigned)(unsigned short)s) << 16);
}
__device__ __forceinline__ void gload_lds16(const void* g, void* l) {
    __builtin_amdgcn_global_load_lds(
        (const __attribute__((address_space(1))) void*)g,
        (__attribute__((address_space(3))) void*)l, 16, 0, 0);
}

// ================= gram partials (256x256 tile, K-slab 512) =================
// grid 512 = 64 batches x 8 slabs; 512 threads = 8 waves (2x4), wave does
// 128x64. X-slab staged 64-K at a time (bf16, swizzled, dbuf = 64KB LDS).
// Row-sum partials via 16-lane shfl. 2 blocks/CU.
__global__ __launch_bounds__(512, 4) void gram_cov(const float* __restrict__ x,
                                                   float* __restrict__ Gp,
                                                   float* __restrict__ Sp) {
    int bid = (blockIdx.x & 7) * 64 + (blockIdx.x >> 3);   // XCD swizzle (512)
    int b = bid >> 3, slab = bid & 7;
    const float* xb = x + (size_t)b * C_ * N_ + (size_t)slab * KW;

    __shared__ short Xs[2][16384];      // [dbuf][256 rows][64 k] bf16, swizzled

    int tid = threadIdx.x;
    int lane = tid & 63, wid = tid >> 6;
    int wr = wid >> 2, wc = wid & 3;    // 2 x 4 wave grid
    int lr = lane & 15, hi = lane >> 4;
    int srow = tid >> 4;                // 0..31
    int scol = (tid & 15) * 4;          // 0..60 (floats)

    float ps[8] = {};
    f32x4 acc[8][4] = {};
    f32x4 rv[8];

    #pragma unroll
    for (int q = 0; q < 8; ++q)
        rv[q] = *(const f32x4*)(xb + (size_t)(q * 32 + srow) * N_ + scol);
    #pragma unroll
    for (int q = 0; q < 8; ++q) {
        int row = q * 32 + srow;
        ps[q] += rv[q][0] + rv[q][1] + rv[q][2] + rv[q][3];
        short4v o;
        #pragma unroll
        for (int e = 0; e < 4; ++e) o[e] = f2bf(rv[q][e]);
        *(short4v*)((char*)Xs[0] + row * 128 + ((scol * 2) ^ ((row & 7) << 4))) = o;
    }
    __syncthreads();

    const int NSTEP = KW / 64;          // 8
    for (int c = 0; c < NSTEP; ++c) {
        if (c + 1 < NSTEP) {            // issue next loads early (T14)
            #pragma unroll
            for (int q = 0; q < 8; ++q)
                rv[q] = *(const f32x4*)(xb + (size_t)(q * 32 + srow) * N_ + (c + 1) * 64 + scol);
        }
        const char* Xb = (const char*)Xs[c & 1];
        #pragma unroll
        for (int ks2 = 0; ks2 < 2; ++ks2) {
            bf16x8 af[8], bfr[4];
            #pragma unroll
            for (int m = 0; m < 8; ++m) {
                int row = wr * 128 + m * 16 + lr;
                af[m] = *(const bf16x8*)(Xb + row * 128 + ((ks2 * 64 + hi * 16) ^ ((row & 7) << 4)));
            }
            #pragma unroll
            for (int n = 0; n < 4; ++n) {
                int row = wc * 64 + n * 16 + lr;
                bfr[n] = *(const bf16x8*)(Xb + row * 128 + ((ks2 * 64 + hi * 16) ^ ((row & 7) << 4)));
            }
            #pragma unroll
            for (int m = 0; m < 8; ++m)
                #pragma unroll
                for (int n = 0; n < 4; ++n)
                    acc[m][n] = __builtin_amdgcn_mfma_f32_16x16x32_bf16(af[m], bfr[n], acc[m][n], 0, 0, 0);
        }
        if (c + 1 < NSTEP) {
            #pragma unroll
            for (int q = 0; q < 8; ++q) {
                int row = q * 32 + srow;
                ps[q] += rv[q][0] + rv[q][1] + rv[q][2] + rv[q][3];
                short4v o;
                #pragma unroll
                for (int e = 0; e < 4; ++e) o[e] = f2bf(rv[q][e]);
                *(short4v*)((char*)Xs[(c + 1) & 1] + row * 128 + ((scol * 2) ^ ((row & 7) << 4))) = o;
            }
        }
        __syncthreads();
    }

    // partial row sums: 16 lanes (same row) shfl-reduce, lane 0 of group writes
    #pragma unroll
    for (int q = 0; q < 8; ++q) {
        float s = ps[q];
        s += __shfl_down(s, 8, 16);
        s += __shfl_down(s, 4, 16);
        s += __shfl_down(s, 2, 16);
        s += __shfl_down(s, 1, 16);
        if ((tid & 15) == 0)
            Sp[((size_t)slab * B_ + b) * C_ + q * 32 + srow] = s;
    }

    // partial gram (fp32)
    float* G = Gp + ((size_t)slab * B_ + b) * MATE;
    #pragma unroll
    for (int m = 0; m < 8; ++m)
        #pragma unroll
        for (int n = 0; n < 4; ++n)
            #pragma unroll
            for (int r = 0; r < 4; ++r) {
                int i = wr * 128 + m * 16 + hi * 4 + r;
                int j = wc * 64 + n * 16 + lr;
                G[(size_t)i * C_ + j] = acc[m][n][r];
            }
}

// ========== trace: S totals + m = tr(cov)/C, 1/m, sqrt(m) per batch ==========
__global__ __launch_bounds__(256) void trace_kernel(const float* __restrict__ Gp,
                                                    const float* __restrict__ Sp,
                                                    float* __restrict__ S,
                                                    float* __restrict__ mArr) {
    int b = blockIdx.x, i = threadIdx.x;
    float s = 0.f, g = 0.f;
    #pragma unroll
    for (int sl = 0; sl < KS; ++sl) {
        s += Sp[((size_t)sl * B_ + b) * C_ + i];
        g += Gp[((size_t)sl * B_ + b) * MATE + (size_t)i * (C_ + 1)];
    }
    S[b * C_ + i] = s;
    float c = (g - s * s * (1.0f / N_)) * (1.0f / (N_ - 1));
    __shared__ float red[256];
    red[i] = c;
    __syncthreads();
    for (int off = 128; off; off >>= 1) {
        if (i < off) red[i] += red[i + off];
        __syncthreads();
    }
    if (i == 0) {
        float m = red[0] * (1.0f / C_);
        mArr[b] = m;
        mArr[64 + b] = 1.0f / m;
        mArr[128 + b] = sqrtf(m);
    }
}

// == init: cov from partials, Y0 = cov/m (bf16), Z1 = 1.5I - 0.5*Y0 (bf16) ==
__global__ __launch_bounds__(256) void init_kernel(const float* __restrict__ Gp,
                                                   const float* __restrict__ S,
                                                   const float* __restrict__ mArr,
                                                   short* __restrict__ Y0,
                                                   short* __restrict__ Z1) {
    int idx = blockIdx.x * 256 + threadIdx.x;
    size_t e0 = (size_t)idx * 4;
    int b = (int)(e0 >> 16);
    int ij = (int)(e0 & 65535);
    int i = ij >> 8, j0 = ij & 255;
    f32x4 g = {};
    #pragma unroll
    for (int sl = 0; sl < KS; ++sl) {
        f32x4 t = *(const f32x4*)(Gp + (size_t)sl * TOTE + e0);
        g[0] += t[0]; g[1] += t[1]; g[2] += t[2]; g[3] += t[3];
    }
    float Si = S[b * C_ + i];
    f32x4 sj = *(const f32x4*)(S + b * C_ + j0);
    float invm = mArr[64 + b];
    const float invN = 1.0f / (float)N_;
    const float invN1 = 1.0f / (float)(N_ - 1);
    short4v y, z;
    #pragma unroll
    for (int q = 0; q < 4; ++q) {
        float cov = (g[q] - Si * sj[q] * invN) * invN1;
        float a = cov * invm;
        y[q] = f2bf(a);
        z[q] = f2bf(((i == j0 + q) ? 1.5f : 0.0f) - 0.5f * a);
    }
    *(short4v*)(Y0 + e0) = y;
    *(short4v*)(Z1 + e0) = z;
}

// ================= NS GEMM (K=256, panels fully in LDS) =================
// acc[i,j] = sum_k A[i,k]*B[j,k]  (all iterates symmetric -> NT form)
// EP: 0 = P bf16 (acc); 1 = YZ' bf16 (1.5*Base - 0.5*acc), optional dual;
//     2 = final: out[b, triu(i,j)] = sqrt(m)*(1.5*Base - 0.5*acc), upper tiles
template<int EP, bool DUAL>
__global__ __launch_bounds__(256, 1) void ns_gemm(
        const short* A0, const short* B0, const short* Ba0, void* C0,
        const short* A1, const short* B1, const short* Ba1, void* C1,
        const float* __restrict__ mArr) {
    int nb = gridDim.x, per = nb >> 3;
    int bid = (blockIdx.x & 7) * per + (blockIdx.x >> 3);  // XCD swizzle
    const short *A = A0, *B = B0, *Ba = Ba0; void* C = C0;
    if (DUAL && bid >= (nb >> 1)) { bid -= nb >> 1; A = A1; B = B1; Ba = Ba1; C = C1; }
    int b, ti, tj;
    if constexpr (EP == 2) {
        b = bid / 3; int t = bid % 3;
        ti = (t == 2) ? 1 : 0; tj = (t == 0) ? 0 : 1;     // (0,0),(0,1),(1,1)
    } else {
        b = bid >> 2; int t = bid & 3;
        ti = t >> 1; tj = t & 1;
    }
    const short* Ap = A + (size_t)b * MATE + (size_t)ti * 128 * C_;
    const short* Bp = B + (size_t)b * MATE + (size_t)tj * 128 * C_;

    __shared__ short As[32768], Bs[32768];   // 64KB each, swizzled layout

    int tid = threadIdx.x, lane = tid & 63, wid = tid >> 6;
    // stage: linear LDS dest, inverse-swizzled global source (rule #21)
    #pragma unroll
    for (int j = 0; j < 16; ++j) {
        int slot = (j * 4 + wid) * 64 + lane;
        int d = slot * 16;
        int row = d >> 9;
        int inner = (d & 511) ^ ((row & 7) << 4);
        gload_lds16((const char*)Ap + (size_t)row * 512 + inner,
                    (char*)As + (size_t)(j * 4 + wid) * 1024);
        gload_lds16((const char*)Bp + (size_t)row * 512 + inner,
                    (char*)Bs + (size_t)(j * 4 + wid) * 1024);
    }
    __syncthreads();

    int wr = wid >> 1, wc = wid & 1;
    int lr = lane & 15, hi = lane >> 4;
    f32x4 acc[4][4] = {};
    #pragma unroll
    for (int ks = 0; ks < 8; ++ks) {
        bf16x8 af[4], bb[4];
        #pragma unroll
        for (int m = 0; m < 4; ++m) {
            int rowa = wr * 64 + m * 16 + lr;
            af[m] = *(const bf16x8*)((const char*)As + rowa * 512 + ((ks * 64 + hi * 16) ^ ((rowa & 7) << 4)));
            int rowb = wc * 64 + m * 16 + lr;
            bb[m] = *(const bf16x8*)((const char*)Bs + rowb * 512 + ((ks * 64 + hi * 16) ^ ((rowb & 7) << 4)));
        }
        #pragma unroll
        for (int m = 0; m < 4; ++m)
            #pragma unroll
            for (int n = 0; n < 4; ++n)
                acc[m][n] = __builtin_amdgcn_mfma_f32_16x16x32_bf16(af[m], bb[n], acc[m][n], 0, 0, 0);
    }

    int r0 = hi * 4;
    float sqm = (EP == 2) ? mArr[128 + b] : 0.f;
    #pragma unroll
    for (int m = 0; m < 4; ++m)
        #pragma unroll
        for (int n = 0; n < 4; ++n)
            #pragma unroll
            for (int r = 0; r < 4; ++r) {
                int i = ti * 128 + wr * 64 + m * 16 + r0 + r;
                int j = tj * 128 + wc * 64 + n * 16 + lr;
                size_t idx = (size_t)b * MATE + (size_t)i * C_ + j;
                float v = acc[m][n][r];
                if constexpr (EP == 0) {
                    ((short*)C)[idx] = f2bf(v);
                } else if constexpr (EP == 1) {
                    ((short*)C)[idx] = f2bf(1.5f * bf2f(Ba[idx]) - 0.5f * v);
                } else {
                    if (j >= i) {
                        size_t o = (size_t)b * TRI + (size_t)i * C_ - (size_t)(i * (i - 1)) / 2 + (j - i);
                        ((float*)C)[o] = sqm * (1.5f * bf2f(Ba[idx]) - 0.5f * v);
                    }
                }
            }
}

extern "C" void kernel_launch(void* const* d_in, const int* in_sizes, int n_in,
                              void* d_out, int out_size, void* d_ws, size_t ws_size,
                              hipStream_t stream) {
    const float* x = (const float*)d_in[0];
    float* out = (float*)d_out;

    float* mArr = (float*)d_ws;                    // 192 floats (m, 1/m, sqrt m)
    float* S    = mArr + 256;                      // 16384
    float* Sp   = S + 16384;                       // KS*B*C = 131072
    float* Gp   = Sp + (size_t)KS * B_ * C_;       // KS*TOTE fp32 = 128MB
    short* bufs = (short*)(Gp + (size_t)KS * TOTE);
    short* M0 = bufs;                              // 5 bf16 matrices, 8MB each
    short* M1 = bufs + TOTE;
    short* M2 = bufs + 2 * TOTE;
    short* M3 = bufs + 3 * TOTE;
    short* M4 = bufs + 4 * TOTE;

    // gram partials + row-sum partials
    gram_cov<<<B_ * KS, 512, 0, stream>>>(x, Gp, Sp);
    // per-batch trace -> m, 1/m, sqrt(m); total row sums
    trace_kernel<<<B_, 256, 0, stream>>>(Gp, Sp, S, mArr);
    // cov assembly: Y0 -> M0, Z1 = 1.5I - 0.5*Y0 -> M1
    init_kernel<<<(int)(TOTE / 4 / 256), 256, 0, stream>>>(Gp, S, mArr, M0, M1);

    // it1 (Z0=I): Y1 = 1.5*Y0 - 0.5*Y0*Y0 -> M2
    ns_gemm<1, false><<<256, 256, 0, stream>>>(M0, M0, M0, M2,
                                               nullptr, nullptr, nullptr, nullptr, nullptr);
    // it2: P1 = Z1*Y1 -> M3
    ns_gemm<0, false><<<256, 256, 0, stream>>>(M1, M2, nullptr, M3,
                                               nullptr, nullptr, nullptr, nullptr, nullptr);
    //      Y2 = 1.5Y1 - 0.5*Y1*P1 -> M4 || Z2 = 1.5Z1 - 0.5*P1*Z1 -> M0
    ns_gemm<1, true><<<512, 256, 0, stream>>>(M2, M3, M2, M4,
                                              M3, M1, M1, M0, nullptr);
    // it3: P2 = Z2*Y2 -> M2
    ns_gemm<0, false><<<256, 256, 0, stream>>>(M0, M4, nullptr, M2,
                                               nullptr, nullptr, nullptr, nullptr, nullptr);
    //      final: out = sqrt(m)*(1.5Y2 - 0.5*Y2*P2), triu-packed, upper tiles
    ns_gemm<2, false><<<B_ * 3, 256, 0, stream>>>(M4, M2, M4, out,
                                                  nullptr, nullptr, nullptr, nullptr, mArr);
}

// Round 7
// 215.884 us; speedup vs baseline: 1.9988x; 1.9988x over previous
//
#include <hip/hip_runtime.h>
#include <math.h>

// MPN-COV: cov = (X X^T - S S^T/N)/(N-1); sqrt via coupled Newton-Schulz
// (3 iters, trace-normalized, Z0=I shortcut); triu-pack fused into final NS
// epilogue.  B=64, C=256, N=4096.  ws ~= 1 GiB.
// Round 7: gram stages fp32 via global_load_lds (NO staging registers ->
// no spill; round-6 spilled via launch_bounds reg cap), bf16 convert at
// fragment read. 1024-thr block, 16 waves, acc 64 regs. Gp partials bf16.
// ns_gemm: K-split staging -> 64 KB LDS -> 2 blocks/CU capacity.

#define B_ 64
#define C_ 256
#define N_ 4096
#define TRI ((C_*(C_+1))/2)
#define MATE (C_*C_)
#define TOTE ((size_t)B_*MATE)
#define KS 8
#define KW (N_/KS)              // 512

typedef __attribute__((ext_vector_type(8))) short bf16x8;
typedef __attribute__((ext_vector_type(4))) short short4v;
typedef __attribute__((ext_vector_type(4))) float f32x4;

__device__ __forceinline__ short f2bf(float f) {        // RNE float->bf16
    unsigned u = __float_as_uint(f);
    return (short)((u + 0x7FFFu + ((u >> 16) & 1u)) >> 16);
}
__device__ __forceinline__ float bf2f(short s) {
    return __uint_as_float(((unsigned)(unsigned short)s) << 16);
}
__device__ __forceinline__ void gload_lds16(const void* g, void* l) {
    __builtin_amdgcn_global_load_lds(
        (const __attribute__((address_space(1))) void*)g,
        (__attribute__((address_space(3))) void*)l, 16, 0, 0);
}
__device__ __forceinline__ bf16x8 cvt8(f32x4 u, f32x4 v) {
    bf16x8 r;
    #pragma unroll
    for (int e = 0; e < 4; ++e) { r[e] = f2bf(u[e]); r[4 + e] = f2bf(v[e]); }
    return r;
}

// ================= gram partials (256x256 tile, K-slab 512) =================
// grid 512 = 64 batches x 8 slabs; 1024 threads = 16 waves (4x4), wave does
// 64x64 (acc 64 regs). fp32 X-slab staged via global_load_lds, 64-k steps,
// dbuf 2x64KB. bf16 conversion at fragment read. Row sums read back from LDS
// (order-agnostic). Gp partials written bf16.
__global__ __launch_bounds__(1024) void gram_cov(const float* __restrict__ x,
                                                 short* __restrict__ Gp,
                                                 float* __restrict__ Sp) {
    int bid = (blockIdx.x & 7) * 64 + (blockIdx.x >> 3);   // XCD swizzle (512)
    int b = bid >> 3, slab = bid & 7;
    const char* xb = (const char*)(x + (size_t)b * C_ * N_ + (size_t)slab * KW);

    __shared__ float Xs[2][16384];      // 2 x [256 rows][64 k] fp32, swizzled

    int tid = threadIdx.x;
    int lane = tid & 63, wid = tid >> 6;
    int wr = wid >> 2, wc = wid & 3;    // 4 x 4 wave grid
    int lr = lane & 15, hi = lane >> 4;

    f32x4 acc[4][4] = {};
    float ps[4] = {};

    // stage step 0: linear LDS dest, inverse-swizzled global source (rule #21)
    #pragma unroll
    for (int q = 0; q < 4; ++q) {
        int d = (q * 1024 + tid) * 16;
        int row = d >> 8;
        int inner = (d & 255) ^ ((row & 7) << 4);
        gload_lds16(xb + (size_t)row * (N_ * 4) + inner, (char*)Xs[0] + d);
    }
    __syncthreads();

    const int NSTEP = KW / 64;          // 8
    for (int c = 0; c < NSTEP; ++c) {
        if (c + 1 < NSTEP) {            // issue next stage before compute
            #pragma unroll
            for (int q = 0; q < 4; ++q) {
                int d = (q * 1024 + tid) * 16;
                int row = d >> 8;
                int inner = (d & 255) ^ ((row & 7) << 4);
                gload_lds16(xb + (size_t)row * (N_ * 4) + (c + 1) * 256 + inner,
                            (char*)Xs[(c + 1) & 1] + d);
            }
        }
        const char* Xb = (const char*)Xs[c & 1];
        // row-sum partials: thread's 4 staged 16B units (swizzle-agnostic)
        #pragma unroll
        for (int q = 0; q < 4; ++q) {
            f32x4 v = *(const f32x4*)(Xb + (size_t)(q * 1024 + tid) * 16);
            ps[q] += v[0] + v[1] + v[2] + v[3];
        }
        #pragma unroll
        for (int ks2 = 0; ks2 < 2; ++ks2) {
            bf16x8 af[4];
            #pragma unroll
            for (int m = 0; m < 4; ++m) {
                int row = wr * 64 + m * 16 + lr;
                int swz = (row & 7) << 4;
                const char* base = Xb + row * 256;
                f32x4 u = *(const f32x4*)(base + ((ks2 * 128 + hi * 32) ^ swz));
                f32x4 v = *(const f32x4*)(base + ((ks2 * 128 + hi * 32 + 16) ^ swz));
                af[m] = cvt8(u, v);
            }
            #pragma unroll
            for (int n = 0; n < 4; ++n) {
                int row = wc * 64 + n * 16 + lr;
                int swz = (row & 7) << 4;
                const char* base = Xb + row * 256;
                f32x4 u = *(const f32x4*)(base + ((ks2 * 128 + hi * 32) ^ swz));
                f32x4 v = *(const f32x4*)(base + ((ks2 * 128 + hi * 32 + 16) ^ swz));
                bf16x8 bb = cvt8(u, v);
                #pragma unroll
                for (int m = 0; m < 4; ++m)
                    acc[m][n] = __builtin_amdgcn_mfma_f32_16x16x32_bf16(af[m], bb, acc[m][n], 0, 0, 0);
            }
        }
        __syncthreads();   // drains staged vmcnt; frees computed buffer
    }

    // row-sum partials: reduce 16 threads sharing a row-unit set
    #pragma unroll
    for (int q = 0; q < 4; ++q) {
        float s = ps[q];
        s += __shfl_down(s, 8, 16);
        s += __shfl_down(s, 4, 16);
        s += __shfl_down(s, 2, 16);
        s += __shfl_down(s, 1, 16);
        if ((tid & 15) == 0)
            Sp[((size_t)slab * B_ + b) * C_ + q * 64 + (tid >> 4)] = s;
    }

    // partial gram -> bf16
    short* G = Gp + ((size_t)slab * B_ + b) * MATE;
    #pragma unroll
    for (int m = 0; m < 4; ++m)
        #pragma unroll
        for (int n = 0; n < 4; ++n)
            #pragma unroll
            for (int r = 0; r < 4; ++r) {
                int i = wr * 64 + m * 16 + hi * 4 + r;
                int j = wc * 64 + n * 16 + lr;
                G[(size_t)i * C_ + j] = f2bf(acc[m][n][r]);
            }
}

// ========== trace: S totals + m = tr(cov)/C, 1/m, sqrt(m) per batch ==========
__global__ __launch_bounds__(256) void trace_kernel(const short* __restrict__ Gp,
                                                    const float* __restrict__ Sp,
                                                    float* __restrict__ S,
                                                    float* __restrict__ mArr) {
    int b = blockIdx.x, i = threadIdx.x;
    float s = 0.f, g = 0.f;
    #pragma unroll
    for (int sl = 0; sl < KS; ++sl) {
        s += Sp[((size_t)sl * B_ + b) * C_ + i];
        g += bf2f(Gp[((size_t)sl * B_ + b) * MATE + (size_t)i * (C_ + 1)]);
    }
    S[b * C_ + i] = s;
    float c = (g - s * s * (1.0f / N_)) * (1.0f / (N_ - 1));
    __shared__ float red[256];
    red[i] = c;
    __syncthreads();
    for (int off = 128; off; off >>= 1) {
        if (i < off) red[i] += red[i + off];
        __syncthreads();
    }
    if (i == 0) {
        float m = red[0] * (1.0f / C_);
        mArr[b] = m;
        mArr[64 + b] = 1.0f / m;
        mArr[128 + b] = sqrtf(m);
    }
}

// == init: cov from partials, Y0 = cov/m (bf16), Z1 = 1.5I - 0.5*Y0 (bf16) ==
__global__ __launch_bounds__(256) void init_kernel(const short* __restrict__ Gp,
                                                   const float* __restrict__ S,
                                                   const float* __restrict__ mArr,
                                                   short* __restrict__ Y0,
                                                   short* __restrict__ Z1) {
    int idx = blockIdx.x * 256 + threadIdx.x;
    size_t e0 = (size_t)idx * 4;
    int b = (int)(e0 >> 16);
    int ij = (int)(e0 & 65535);
    int i = ij >> 8, j0 = ij & 255;
    f32x4 g = {};
    #pragma unroll
    for (int sl = 0; sl < KS; ++sl) {
        short4v t = *(const short4v*)(Gp + (size_t)sl * TOTE + e0);
        g[0] += bf2f(t[0]); g[1] += bf2f(t[1]); g[2] += bf2f(t[2]); g[3] += bf2f(t[3]);
    }
    float Si = S[b * C_ + i];
    f32x4 sj = *(const f32x4*)(S + b * C_ + j0);
    float invm = mArr[64 + b];
    const float invN = 1.0f / (float)N_;
    const float invN1 = 1.0f / (float)(N_ - 1);
    short4v y, z;
    #pragma unroll
    for (int q = 0; q < 4; ++q) {
        float cov = (g[q] - Si * sj[q] * invN) * invN1;
        float a = cov * invm;
        y[q] = f2bf(a);
        z[q] = f2bf(((i == j0 + q) ? 1.5f : 0.0f) - 0.5f * a);
    }
    *(short4v*)(Y0 + e0) = y;
    *(short4v*)(Z1 + e0) = z;
}

// ================= NS GEMM (K=256 in 2 staged halves, 64 KB LDS) =============
// acc[i,j] = sum_k A[i,k]*B[j,k]  (all iterates symmetric -> NT form)
// EP: 0 = P bf16 (acc); 1 = YZ' bf16 (1.5*Base - 0.5*acc), optional dual;
//     2 = final: out[b, triu(i,j)] = sqrt(m)*(1.5*Base - 0.5*acc), upper tiles
template<int EP, bool DUAL>
__global__ __launch_bounds__(256) void ns_gemm(
        const short* A0, const short* B0, const short* Ba0, void* C0,
        const short* A1, const short* B1, const short* Ba1, void* C1,
        const float* __restrict__ mArr) {
    int nb = gridDim.x, per = nb >> 3;
    int bid = (blockIdx.x & 7) * per + (blockIdx.x >> 3);  // XCD swizzle
    const short *A = A0, *B = B0, *Ba = Ba0; void* C = C0;
    if (DUAL && bid >= (nb >> 1)) { bid -= nb >> 1; A = A1; B = B1; Ba = Ba1; C = C1; }
    int b, ti, tj;
    if constexpr (EP == 2) {
        b = bid / 3; int t = bid % 3;
        ti = (t == 2) ? 1 : 0; tj = (t == 0) ? 0 : 1;     // (0,0),(0,1),(1,1)
    } else {
        b = bid >> 2; int t = bid & 3;
        ti = t >> 1; tj = t & 1;
    }
    const short* Ap = A + (size_t)b * MATE + (size_t)ti * 128 * C_;
    const short* Bp = B + (size_t)b * MATE + (size_t)tj * 128 * C_;

    __shared__ short As[16384], Bs[16384];   // 32 KB each: [128 rows][128 k]

    int tid = threadIdx.x, lane = tid & 63, wid = tid >> 6;
    int wr = wid >> 1, wc = wid & 1;
    int lr = lane & 15, hi = lane >> 4;
    f32x4 acc[4][4] = {};

    for (int h = 0; h < 2; ++h) {
        // stage half h: linear LDS dest, inverse-swizzled source (rule #21)
        #pragma unroll
        for (int q = 0; q < 8; ++q) {
            int d = (q * 256 + tid) * 16;
            int row = d >> 8;
            int inner = (d & 255) ^ ((row & 7) << 4);
            gload_lds16((const char*)Ap + (size_t)row * 512 + h * 256 + inner,
                        (char*)As + d);
            gload_lds16((const char*)Bp + (size_t)row * 512 + h * 256 + inner,
                        (char*)Bs + d);
        }
        __syncthreads();
        #pragma unroll
        for (int ks = 0; ks < 4; ++ks) {
            bf16x8 af[4], bb[4];
            #pragma unroll
            for (int m = 0; m < 4; ++m) {
                int rowa = wr * 64 + m * 16 + lr;
                af[m] = *(const bf16x8*)((const char*)As + rowa * 256 +
                                         ((ks * 64 + hi * 16) ^ ((rowa & 7) << 4)));
                int rowb = wc * 64 + m * 16 + lr;
                bb[m] = *(const bf16x8*)((const char*)Bs + rowb * 256 +
                                         ((ks * 64 + hi * 16) ^ ((rowb & 7) << 4)));
            }
            #pragma unroll
            for (int m = 0; m < 4; ++m)
                #pragma unroll
                for (int n = 0; n < 4; ++n)
                    acc[m][n] = __builtin_amdgcn_mfma_f32_16x16x32_bf16(af[m], bb[n], acc[m][n], 0, 0, 0);
        }
        if (h == 0) __syncthreads();   // buffer reuse for half 1
    }

    int r0 = hi * 4;
    float sqm = (EP == 2) ? mArr[128 + b] : 0.f;
    #pragma unroll
    for (int m = 0; m < 4; ++m)
        #pragma unroll
        for (int n = 0; n < 4; ++n)
            #pragma unroll
            for (int r = 0; r < 4; ++r) {
                int i = ti * 128 + wr * 64 + m * 16 + r0 + r;
                int j = tj * 128 + wc * 64 + n * 16 + lr;
                size_t idx = (size_t)b * MATE + (size_t)i * C_ + j;
                float v = acc[m][n][r];
                if constexpr (EP == 0) {
                    ((short*)C)[idx] = f2bf(v);
                } else if constexpr (EP == 1) {
                    ((short*)C)[idx] = f2bf(1.5f * bf2f(Ba[idx]) - 0.5f * v);
                } else {
                    if (j >= i) {
                        size_t o = (size_t)b * TRI + (size_t)i * C_ - (size_t)(i * (i - 1)) / 2 + (j - i);
                        ((float*)C)[o] = sqm * (1.5f * bf2f(Ba[idx]) - 0.5f * v);
                    }
                }
            }
}

extern "C" void kernel_launch(void* const* d_in, const int* in_sizes, int n_in,
                              void* d_out, int out_size, void* d_ws, size_t ws_size,
                              hipStream_t stream) {
    const float* x = (const float*)d_in[0];
    float* out = (float*)d_out;

    float* mArr = (float*)d_ws;                    // 256 floats (m, 1/m, sqrt m)
    float* S    = mArr + 256;                      // 16384
    float* Sp   = S + 16384;                       // KS*B*C = 131072
    short* Gp   = (short*)(Sp + (size_t)KS * B_ * C_);   // KS*TOTE bf16 = 64MB
    short* bufs = Gp + (size_t)KS * TOTE;
    short* M0 = bufs;                              // 5 bf16 matrices, 8MB each
    short* M1 = bufs + TOTE;
    short* M2 = bufs + 2 * TOTE;
    short* M3 = bufs + 3 * TOTE;
    short* M4 = bufs + 4 * TOTE;

    // gram partials (bf16) + row-sum partials
    gram_cov<<<B_ * KS, 1024, 0, stream>>>(x, Gp, Sp);
    // per-batch trace -> m, 1/m, sqrt(m); total row sums
    trace_kernel<<<B_, 256, 0, stream>>>(Gp, Sp, S, mArr);
    // cov assembly: Y0 -> M0, Z1 = 1.5I - 0.5*Y0 -> M1
    init_kernel<<<(int)(TOTE / 4 / 256), 256, 0, stream>>>(Gp, S, mArr, M0, M1);

    // it1 (Z0=I): Y1 = 1.5*Y0 - 0.5*Y0*Y0 -> M2
    ns_gemm<1, false><<<256, 256, 0, stream>>>(M0, M0, M0, M2,
                                               nullptr, nullptr, nullptr, nullptr, nullptr);
    // it2: P1 = Z1*Y1 -> M3
    ns_gemm<0, false><<<256, 256, 0, stream>>>(M1, M2, nullptr, M3,
                                               nullptr, nullptr, nullptr, nullptr, nullptr);
    //      Y2 = 1.5Y1 - 0.5*Y1*P1 -> M4 || Z2 = 1.5Z1 - 0.5*P1*Z1 -> M0
    ns_gemm<1, true><<<512, 256, 0, stream>>>(M2, M3, M2, M4,
                                              M3, M1, M1, M0, nullptr);
    // it3: P2 = Z2*Y2 -> M2
    ns_gemm<0, false><<<256, 256, 0, stream>>>(M0, M4, nullptr, M2,
                                               nullptr, nullptr, nullptr, nullptr, nullptr);
    //      final: out = sqrt(m)*(1.5Y2 - 0.5*Y2*P2), triu-packed, upper tiles
    ns_gemm<2, false><<<B_ * 3, 256, 0, stream>>>(M4, M2, M4, out,
                                                  nullptr, nullptr, nullptr, nullptr, mArr);
}

// Round 8
// 206.133 us; speedup vs baseline: 2.0934x; 1.0473x over previous
//
#include <hip/hip_runtime.h>
#include <math.h>

// MPN-COV: cov = (X X^T - S S^T/N)/(N-1); sqrt via coupled Newton-Schulz
// (3 iters, trace-normalized, Z0=I shortcut); triu-pack fused into final NS
// epilogue.  B=64, C=256, N=4096.  ws ~= 1 GiB.
// Round 8: KS 8->4 (gram = single 256-block pass at 1 blk/CU; Gp traffic
// halved to 32 MB); init vectorized to 16B. Gram stages fp32 via
// global_load_lds (no staging regs), bf16 convert at fragment read.

#define B_ 64
#define C_ 256
#define N_ 4096
#define TRI ((C_*(C_+1))/2)
#define MATE (C_*C_)
#define TOTE ((size_t)B_*MATE)
#define KS 4
#define KW (N_/KS)              // 1024

typedef __attribute__((ext_vector_type(8))) short bf16x8;
typedef __attribute__((ext_vector_type(4))) short short4v;
typedef __attribute__((ext_vector_type(4))) float f32x4;

__device__ __forceinline__ short f2bf(float f) {        // RNE float->bf16
    unsigned u = __float_as_uint(f);
    return (short)((u + 0x7FFFu + ((u >> 16) & 1u)) >> 16);
}
__device__ __forceinline__ float bf2f(short s) {
    return __uint_as_float(((unsigned)(unsigned short)s) << 16);
}
__device__ __forceinline__ void gload_lds16(const void* g, void* l) {
    __builtin_amdgcn_global_load_lds(
        (const __attribute__((address_space(1))) void*)g,
        (__attribute__((address_space(3))) void*)l, 16, 0, 0);
}
__device__ __forceinline__ bf16x8 cvt8(f32x4 u, f32x4 v) {
    bf16x8 r;
    #pragma unroll
    for (int e = 0; e < 4; ++e) { r[e] = f2bf(u[e]); r[4 + e] = f2bf(v[e]); }
    return r;
}

// ================= gram partials (256x256 tile, K-slab 1024) ================
// grid 256 = 64 batches x 4 slabs; 1024 threads = 16 waves (4x4), wave does
// 64x64 (acc 64 regs). fp32 X-slab staged via global_load_lds, 64-k steps,
// dbuf 2x64KB. bf16 conversion at fragment read. Gp partials bf16.
__global__ __launch_bounds__(1024) void gram_cov(const float* __restrict__ x,
                                                 short* __restrict__ Gp,
                                                 float* __restrict__ Sp) {
    int bid = (blockIdx.x & 7) * 32 + (blockIdx.x >> 3);   // XCD swizzle (256)
    int b = bid >> 2, slab = bid & 3;
    const char* xb = (const char*)(x + (size_t)b * C_ * N_ + (size_t)slab * KW);

    __shared__ float Xs[2][16384];      // 2 x [256 rows][64 k] fp32, swizzled

    int tid = threadIdx.x;
    int lane = tid & 63, wid = tid >> 6;
    int wr = wid >> 2, wc = wid & 3;    // 4 x 4 wave grid
    int lr = lane & 15, hi = lane >> 4;

    f32x4 acc[4][4] = {};
    float ps[4] = {};

    // stage step 0: linear LDS dest, inverse-swizzled global source (rule #21)
    #pragma unroll
    for (int q = 0; q < 4; ++q) {
        int d = (q * 1024 + tid) * 16;
        int row = d >> 8;
        int inner = (d & 255) ^ ((row & 7) << 4);
        gload_lds16(xb + (size_t)row * (N_ * 4) + inner, (char*)Xs[0] + d);
    }
    __syncthreads();

    const int NSTEP = KW / 64;          // 16
    for (int c = 0; c < NSTEP; ++c) {
        if (c + 1 < NSTEP) {            // issue next stage before compute
            #pragma unroll
            for (int q = 0; q < 4; ++q) {
                int d = (q * 1024 + tid) * 16;
                int row = d >> 8;
                int inner = (d & 255) ^ ((row & 7) << 4);
                gload_lds16(xb + (size_t)row * (N_ * 4) + (c + 1) * 256 + inner,
                            (char*)Xs[(c + 1) & 1] + d);
            }
        }
        const char* Xb = (const char*)Xs[c & 1];
        // row-sum partials: thread's 4 staged 16B units (swizzle-agnostic)
        #pragma unroll
        for (int q = 0; q < 4; ++q) {
            f32x4 v = *(const f32x4*)(Xb + (size_t)(q * 1024 + tid) * 16);
            ps[q] += v[0] + v[1] + v[2] + v[3];
        }
        #pragma unroll
        for (int ks2 = 0; ks2 < 2; ++ks2) {
            bf16x8 af[4];
            #pragma unroll
            for (int m = 0; m < 4; ++m) {
                int row = wr * 64 + m * 16 + lr;
                int swz = (row & 7) << 4;
                const char* base = Xb + row * 256;
                f32x4 u = *(const f32x4*)(base + ((ks2 * 128 + hi * 32) ^ swz));
                f32x4 v = *(const f32x4*)(base + ((ks2 * 128 + hi * 32 + 16) ^ swz));
                af[m] = cvt8(u, v);
            }
            #pragma unroll
            for (int n = 0; n < 4; ++n) {
                int row = wc * 64 + n * 16 + lr;
                int swz = (row & 7) << 4;
                const char* base = Xb + row * 256;
                f32x4 u = *(const f32x4*)(base + ((ks2 * 128 + hi * 32) ^ swz));
                f32x4 v = *(const f32x4*)(base + ((ks2 * 128 + hi * 32 + 16) ^ swz));
                bf16x8 bb = cvt8(u, v);
                #pragma unroll
                for (int m = 0; m < 4; ++m)
                    acc[m][n] = __builtin_amdgcn_mfma_f32_16x16x32_bf16(af[m], bb, acc[m][n], 0, 0, 0);
            }
        }
        __syncthreads();   // drains staged vmcnt; frees computed buffer
    }

    // row-sum partials: reduce 16 threads sharing a row-unit set
    #pragma unroll
    for (int q = 0; q < 4; ++q) {
        float s = ps[q];
        s += __shfl_down(s, 8, 16);
        s += __shfl_down(s, 4, 16);
        s += __shfl_down(s, 2, 16);
        s += __shfl_down(s, 1, 16);
        if ((tid & 15) == 0)
            Sp[((size_t)slab * B_ + b) * C_ + q * 64 + (tid >> 4)] = s;
    }

    // partial gram -> bf16
    short* G = Gp + ((size_t)slab * B_ + b) * MATE;
    #pragma unroll
    for (int m = 0; m < 4; ++m)
        #pragma unroll
        for (int n = 0; n < 4; ++n)
            #pragma unroll
            for (int r = 0; r < 4; ++r) {
                int i = wr * 64 + m * 16 + hi * 4 + r;
                int j = wc * 64 + n * 16 + lr;
                G[(size_t)i * C_ + j] = f2bf(acc[m][n][r]);
            }
}

// ========== trace: S totals + m = tr(cov)/C, 1/m, sqrt(m) per batch ==========
__global__ __launch_bounds__(256) void trace_kernel(const short* __restrict__ Gp,
                                                    const float* __restrict__ Sp,
                                                    float* __restrict__ S,
                                                    float* __restrict__ mArr) {
    int b = blockIdx.x, i = threadIdx.x;
    float s = 0.f, g = 0.f;
    #pragma unroll
    for (int sl = 0; sl < KS; ++sl) {
        s += Sp[((size_t)sl * B_ + b) * C_ + i];
        g += bf2f(Gp[((size_t)sl * B_ + b) * MATE + (size_t)i * (C_ + 1)]);
    }
    S[b * C_ + i] = s;
    float c = (g - s * s * (1.0f / N_)) * (1.0f / (N_ - 1));
    __shared__ float red[256];
    red[i] = c;
    __syncthreads();
    for (int off = 128; off; off >>= 1) {
        if (i < off) red[i] += red[i + off];
        __syncthreads();
    }
    if (i == 0) {
        float m = red[0] * (1.0f / C_);
        mArr[b] = m;
        mArr[64 + b] = 1.0f / m;
        mArr[128 + b] = sqrtf(m);
    }
}

// == init: cov from partials, Y0 = cov/m (bf16), Z1 = 1.5I - 0.5*Y0 (bf16) ==
__global__ __launch_bounds__(256) void init_kernel(const short* __restrict__ Gp,
                                                   const float* __restrict__ S,
                                                   const float* __restrict__ mArr,
                                                   short* __restrict__ Y0,
                                                   short* __restrict__ Z1) {
    int idx = blockIdx.x * 256 + threadIdx.x;
    size_t e0 = (size_t)idx * 8;                // 8 elems / thread (16B)
    int b = (int)(e0 >> 16);
    int ij = (int)(e0 & 65535);
    int i = ij >> 8, j0 = ij & 255;
    float g[8] = {};
    #pragma unroll
    for (int sl = 0; sl < KS; ++sl) {
        bf16x8 t = *(const bf16x8*)(Gp + (size_t)sl * TOTE + e0);
        #pragma unroll
        for (int q = 0; q < 8; ++q) g[q] += bf2f(t[q]);
    }
    float Si = S[b * C_ + i];
    f32x4 sjA = *(const f32x4*)(S + b * C_ + j0);
    f32x4 sjB = *(const f32x4*)(S + b * C_ + j0 + 4);
    float invm = mArr[64 + b];
    const float invN = 1.0f / (float)N_;
    const float invN1 = 1.0f / (float)(N_ - 1);
    bf16x8 y, z;
    #pragma unroll
    for (int q = 0; q < 8; ++q) {
        float sj = (q < 4) ? sjA[q] : sjB[q - 4];
        float cov = (g[q] - Si * sj * invN) * invN1;
        float a = cov * invm;
        y[q] = f2bf(a);
        z[q] = f2bf(((i == j0 + q) ? 1.5f : 0.0f) - 0.5f * a);
    }
    *(bf16x8*)(Y0 + e0) = y;
    *(bf16x8*)(Z1 + e0) = z;
}

// ================= NS GEMM (K=256 in 2 staged halves, 64 KB LDS) =============
// acc[i,j] = sum_k A[i,k]*B[j,k]  (all iterates symmetric -> NT form)
// EP: 0 = P bf16 (acc); 1 = YZ' bf16 (1.5*Base - 0.5*acc), optional dual;
//     2 = final: out[b, triu(i,j)] = sqrt(m)*(1.5*Base - 0.5*acc), upper tiles
template<int EP, bool DUAL>
__global__ __launch_bounds__(256) void ns_gemm(
        const short* A0, const short* B0, const short* Ba0, void* C0,
        const short* A1, const short* B1, const short* Ba1, void* C1,
        const float* __restrict__ mArr) {
    int nb = gridDim.x, per = nb >> 3;
    int bid = (blockIdx.x & 7) * per + (blockIdx.x >> 3);  // XCD swizzle
    const short *A = A0, *B = B0, *Ba = Ba0; void* C = C0;
    if (DUAL && bid >= (nb >> 1)) { bid -= nb >> 1; A = A1; B = B1; Ba = Ba1; C = C1; }
    int b, ti, tj;
    if constexpr (EP == 2) {
        b = bid / 3; int t = bid % 3;
        ti = (t == 2) ? 1 : 0; tj = (t == 0) ? 0 : 1;     // (0,0),(0,1),(1,1)
    } else {
        b = bid >> 2; int t = bid & 3;
        ti = t >> 1; tj = t & 1;
    }
    const short* Ap = A + (size_t)b * MATE + (size_t)ti * 128 * C_;
    const short* Bp = B + (size_t)b * MATE + (size_t)tj * 128 * C_;

    __shared__ short As[16384], Bs[16384];   // 32 KB each: [128 rows][128 k]

    int tid = threadIdx.x, lane = tid & 63, wid = tid >> 6;
    int wr = wid >> 1, wc = wid & 1;
    int lr = lane & 15, hi = lane >> 4;
    f32x4 acc[4][4] = {};

    for (int h = 0; h < 2; ++h) {
        // stage half h: linear LDS dest, inverse-swizzled source (rule #21)
        #pragma unroll
        for (int q = 0; q < 8; ++q) {
            int d = (q * 256 + tid) * 16;
            int row = d >> 8;
            int inner = (d & 255) ^ ((row & 7) << 4);
            gload_lds16((const char*)Ap + (size_t)row * 512 + h * 256 + inner,
                        (char*)As + d);
            gload_lds16((const char*)Bp + (size_t)row * 512 + h * 256 + inner,
                        (char*)Bs + d);
        }
        __syncthreads();
        #pragma unroll
        for (int ks = 0; ks < 4; ++ks) {
            bf16x8 af[4], bb[4];
            #pragma unroll
            for (int m = 0; m < 4; ++m) {
                int rowa = wr * 64 + m * 16 + lr;
                af[m] = *(const bf16x8*)((const char*)As + rowa * 256 +
                                         ((ks * 64 + hi * 16) ^ ((rowa & 7) << 4)));
                int rowb = wc * 64 + m * 16 + lr;
                bb[m] = *(const bf16x8*)((const char*)Bs + rowb * 256 +
                                         ((ks * 64 + hi * 16) ^ ((rowb & 7) << 4)));
            }
            #pragma unroll
            for (int m = 0; m < 4; ++m)
                #pragma unroll
                for (int n = 0; n < 4; ++n)
                    acc[m][n] = __builtin_amdgcn_mfma_f32_16x16x32_bf16(af[m], bb[n], acc[m][n], 0, 0, 0);
        }
        if (h == 0) __syncthreads();   // buffer reuse for half 1
    }

    int r0 = hi * 4;
    float sqm = (EP == 2) ? mArr[128 + b] : 0.f;
    #pragma unroll
    for (int m = 0; m < 4; ++m)
        #pragma unroll
        for (int n = 0; n < 4; ++n)
            #pragma unroll
            for (int r = 0; r < 4; ++r) {
                int i = ti * 128 + wr * 64 + m * 16 + r0 + r;
                int j = tj * 128 + wc * 64 + n * 16 + lr;
                size_t idx = (size_t)b * MATE + (size_t)i * C_ + j;
                float v = acc[m][n][r];
                if constexpr (EP == 0) {
                    ((short*)C)[idx] = f2bf(v);
                } else if constexpr (EP == 1) {
                    ((short*)C)[idx] = f2bf(1.5f * bf2f(Ba[idx]) - 0.5f * v);
                } else {
                    if (j >= i) {
                        size_t o = (size_t)b * TRI + (size_t)i * C_ - (size_t)(i * (i - 1)) / 2 + (j - i);
                        ((float*)C)[o] = sqm * (1.5f * bf2f(Ba[idx]) - 0.5f * v);
                    }
                }
            }
}

extern "C" void kernel_launch(void* const* d_in, const int* in_sizes, int n_in,
                              void* d_out, int out_size, void* d_ws, size_t ws_size,
                              hipStream_t stream) {
    const float* x = (const float*)d_in[0];
    float* out = (float*)d_out;

    float* mArr = (float*)d_ws;                    // 256 floats (m, 1/m, sqrt m)
    float* S    = mArr + 256;                      // 16384
    float* Sp   = S + 16384;                       // KS*B*C = 65536
    short* Gp   = (short*)(Sp + (size_t)KS * B_ * C_);   // KS*TOTE bf16 = 32MB
    short* bufs = Gp + (size_t)KS * TOTE;
    short* M0 = bufs;                              // 5 bf16 matrices, 8MB each
    short* M1 = bufs + TOTE;
    short* M2 = bufs + 2 * TOTE;
    short* M3 = bufs + 3 * TOTE;
    short* M4 = bufs + 4 * TOTE;

    // gram partials (bf16) + row-sum partials
    gram_cov<<<B_ * KS, 1024, 0, stream>>>(x, Gp, Sp);
    // per-batch trace -> m, 1/m, sqrt(m); total row sums
    trace_kernel<<<B_, 256, 0, stream>>>(Gp, Sp, S, mArr);
    // cov assembly: Y0 -> M0, Z1 = 1.5I - 0.5*Y0 -> M1
    init_kernel<<<(int)(TOTE / 8 / 256), 256, 0, stream>>>(Gp, S, mArr, M0, M1);

    // it1 (Z0=I): Y1 = 1.5*Y0 - 0.5*Y0*Y0 -> M2
    ns_gemm<1, false><<<256, 256, 0, stream>>>(M0, M0, M0, M2,
                                               nullptr, nullptr, nullptr, nullptr, nullptr);
    // it2: P1 = Z1*Y1 -> M3
    ns_gemm<0, false><<<256, 256, 0, stream>>>(M1, M2, nullptr, M3,
                                               nullptr, nullptr, nullptr, nullptr, nullptr);
    //      Y2 = 1.5Y1 - 0.5*Y1*P1 -> M4 || Z2 = 1.5Z1 - 0.5*P1*Z1 -> M0
    ns_gemm<1, true><<<512, 256, 0, stream>>>(M2, M3, M2, M4,
                                              M3, M1, M1, M0, nullptr);
    // it3: P2 = Z2*Y2 -> M2
    ns_gemm<0, false><<<256, 256, 0, stream>>>(M0, M4, nullptr, M2,
                                               nullptr, nullptr, nullptr, nullptr, nullptr);
    //      final: out = sqrt(m)*(1.5Y2 - 0.5*Y2*P2), triu-packed, upper tiles
    ns_gemm<2, false><<<B_ * 3, 256, 0, stream>>>(M4, M2, M4, out,
                                                  nullptr, nullptr, nullptr, nullptr, mArr);
}

// Round 9
// 195.015 us; speedup vs baseline: 2.2127x; 1.0570x over previous
//
#include <hip/hip_runtime.h>
#include <hip/hip_bf16.h>
#include <math.h>

// MPN-COV: cov = (X X^T - S S^T/N)/(N-1); sqrt via coupled Newton-Schulz
// (3 iters, trace-normalized, Z0=I shortcut); triu-pack fused into final NS
// epilogue.  B=64, C=256, N=4096.  ws ~= 1 GiB.
// Round 9: gram pipeline fix — rowsum ds_reads BEFORE gload issue, fragment
// reads via inline-asm ds_read_b128 (opaque to the waitcnt pass, rule #18)
// so the c+1 staging DMA stays in flight under compute; native cvt_pk bf16.

#define B_ 64
#define C_ 256
#define N_ 4096
#define TRI ((C_*(C_+1))/2)
#define MATE (C_*C_)
#define TOTE ((size_t)B_*MATE)
#define KS 4
#define KW (N_/KS)              // 1024

typedef __attribute__((ext_vector_type(8))) short bf16x8;
typedef __attribute__((ext_vector_type(4))) short short4v;
typedef __attribute__((ext_vector_type(4))) float f32x4;

__device__ __forceinline__ short f2bf(float f) {        // RNE float->bf16
    unsigned u = __float_as_uint(f);
    return (short)((u + 0x7FFFu + ((u >> 16) & 1u)) >> 16);
}
__device__ __forceinline__ float bf2f(short s) {
    return __uint_as_float(((unsigned)(unsigned short)s) << 16);
}
__device__ __forceinline__ void gload_lds16(const void* g, void* l) {
    __builtin_amdgcn_global_load_lds(
        (const __attribute__((address_space(1))) void*)g,
        (__attribute__((address_space(3))) void*)l, 16, 0, 0);
}
// native convert (compiler emits v_cvt_pk_bf16_f32; RNE) — m240: use casts
__device__ __forceinline__ bf16x8 cvt8n(f32x4 u, f32x4 v) {
    bf16x8 r;
    #pragma unroll
    for (int e = 0; e < 4; ++e) {
        __hip_bfloat16 a = __float2bfloat16(u[e]);
        __hip_bfloat16 b = __float2bfloat16(v[e]);
        r[e]     = *reinterpret_cast<short*>(&a);
        r[4 + e] = *reinterpret_cast<short*>(&b);
    }
    return r;
}
// opaque 16B LDS read: waitcnt pass can't see it -> no vmcnt(0) pessimization
__device__ __forceinline__ f32x4 ds_read16(unsigned addr) {
    f32x4 r;
    asm volatile("ds_read_b128 %0, %1" : "=v"(r) : "v"(addr));
    return r;
}
__device__ __forceinline__ void lgkm0_fence() {
    asm volatile("s_waitcnt lgkmcnt(0)" ::: "memory");
    __builtin_amdgcn_sched_barrier(0);
}

// ================= gram partials (256x256 tile, K-slab 1024) ================
// grid 256 = 64 batches x 4 slabs; 1024 threads = 16 waves (4x4), wave does
// 64x64 (acc 64 regs). fp32 X-slab staged via global_load_lds (dbuf 2x64KB);
// next-step DMA overlaps compute via asm ds_reads. Gp partials bf16.
__global__ __launch_bounds__(1024) void gram_cov(const float* __restrict__ x,
                                                 short* __restrict__ Gp,
                                                 float* __restrict__ Sp) {
    int bid = (blockIdx.x & 7) * 32 + (blockIdx.x >> 3);   // XCD swizzle (256)
    int b = bid >> 2, slab = bid & 3;
    const char* xb = (const char*)(x + (size_t)b * C_ * N_ + (size_t)slab * KW);

    __shared__ float Xs[2][16384];      // 2 x [256 rows][64 k] fp32, swizzled

    int tid = threadIdx.x;
    int lane = tid & 63, wid = tid >> 6;
    int wr = wid >> 2, wc = wid & 3;    // 4 x 4 wave grid
    int lr = lane & 15, hi = lane >> 4;

    unsigned xs0 = (unsigned)(unsigned long long)
        (__attribute__((address_space(3))) char*)&Xs[0][0];
    unsigned swz = (unsigned)((lr & 7) << 4);
    unsigned rowA = (unsigned)((wr * 64 + lr) * 256);   // byte row base, A frags
    unsigned rowB = (unsigned)((wc * 64 + lr) * 256);   // byte row base, B frags

    f32x4 acc[4][4] = {};
    float ps[4] = {};

    // stage step 0: linear LDS dest, inverse-swizzled global source (rule #21)
    #pragma unroll
    for (int q = 0; q < 4; ++q) {
        int d = (q * 1024 + tid) * 16;
        int row = d >> 8;
        int inner = (d & 255) ^ ((row & 7) << 4);
        gload_lds16(xb + (size_t)row * (N_ * 4) + inner, (char*)Xs[0] + d);
    }
    __syncthreads();

    const int NSTEP = KW / 64;          // 16
    for (int c = 0; c < NSTEP; ++c) {
        const char* Xb = (const char*)Xs[c & 1];
        // (1) row-sum reads FIRST (no vmem outstanding -> no wait inserted)
        #pragma unroll
        for (int q = 0; q < 4; ++q) {
            f32x4 v = *(const f32x4*)(Xb + (size_t)(q * 1024 + tid) * 16);
            ps[q] += v[0] + v[1] + v[2] + v[3];
        }
        // (2) issue next-step staging; stays in flight under compute below
        if (c + 1 < NSTEP) {
            #pragma unroll
            for (int q = 0; q < 4; ++q) {
                int d = (q * 1024 + tid) * 16;
                int row = d >> 8;
                int inner = (d & 255) ^ ((row & 7) << 4);
                gload_lds16(xb + (size_t)row * (N_ * 4) + (c + 1) * 256 + inner,
                            (char*)Xs[(c + 1) & 1] + d);
            }
        }
        // (3) fragment reads via asm + manual lgkm waits; cvt; MFMA
        unsigned xsb = xs0 + (unsigned)((c & 1) * 65536);
        #pragma unroll
        for (int ks2 = 0; ks2 < 2; ++ks2) {
            unsigned o1 = ((unsigned)(ks2 * 128 + hi * 32)) ^ swz;
            f32x4 ua[4], va[4];
            #pragma unroll
            for (int m = 0; m < 4; ++m) {
                unsigned a = xsb + rowA + (unsigned)(m * 4096) + o1;
                ua[m] = ds_read16(a);
                va[m] = ds_read16(a ^ 16u);
            }
            lgkm0_fence();
            bf16x8 af[4];
            #pragma unroll
            for (int m = 0; m < 4; ++m) af[m] = cvt8n(ua[m], va[m]);
            f32x4 ub[4], vb[4];
            #pragma unroll
            for (int n = 0; n < 4; ++n) {
                unsigned a = xsb + rowB + (unsigned)(n * 4096) + o1;
                ub[n] = ds_read16(a);
                vb[n] = ds_read16(a ^ 16u);
            }
            lgkm0_fence();
            #pragma unroll
            for (int n = 0; n < 4; ++n) {
                bf16x8 bb = cvt8n(ub[n], vb[n]);
                #pragma unroll
                for (int m = 0; m < 4; ++m)
                    acc[m][n] = __builtin_amdgcn_mfma_f32_16x16x32_bf16(af[m], bb, acc[m][n], 0, 0, 0);
            }
        }
        __syncthreads();   // drains vmcnt (gload c+1) exactly where required
    }

    // row-sum partials: reduce 16 threads sharing a row-unit set
    #pragma unroll
    for (int q = 0; q < 4; ++q) {
        float s = ps[q];
        s += __shfl_down(s, 8, 16);
        s += __shfl_down(s, 4, 16);
        s += __shfl_down(s, 2, 16);
        s += __shfl_down(s, 1, 16);
        if ((tid & 15) == 0)
            Sp[((size_t)slab * B_ + b) * C_ + q * 64 + (tid >> 4)] = s;
    }

    // partial gram -> bf16
    short* G = Gp + ((size_t)slab * B_ + b) * MATE;
    #pragma unroll
    for (int m = 0; m < 4; ++m)
        #pragma unroll
        for (int n = 0; n < 4; ++n)
            #pragma unroll
            for (int r = 0; r < 4; ++r) {
                int i = wr * 64 + m * 16 + hi * 4 + r;
                int j = wc * 64 + n * 16 + lr;
                G[(size_t)i * C_ + j] = f2bf(acc[m][n][r]);
            }
}

// ========== trace: S totals + m = tr(cov)/C, 1/m, sqrt(m) per batch ==========
__global__ __launch_bounds__(256) void trace_kernel(const short* __restrict__ Gp,
                                                    const float* __restrict__ Sp,
                                                    float* __restrict__ S,
                                                    float* __restrict__ mArr) {
    int b = blockIdx.x, i = threadIdx.x;
    float s = 0.f, g = 0.f;
    #pragma unroll
    for (int sl = 0; sl < KS; ++sl) {
        s += Sp[((size_t)sl * B_ + b) * C_ + i];
        g += bf2f(Gp[((size_t)sl * B_ + b) * MATE + (size_t)i * (C_ + 1)]);
    }
    S[b * C_ + i] = s;
    float c = (g - s * s * (1.0f / N_)) * (1.0f / (N_ - 1));
    __shared__ float red[256];
    red[i] = c;
    __syncthreads();
    for (int off = 128; off; off >>= 1) {
        if (i < off) red[i] += red[i + off];
        __syncthreads();
    }
    if (i == 0) {
        float m = red[0] * (1.0f / C_);
        mArr[b] = m;
        mArr[64 + b] = 1.0f / m;
        mArr[128 + b] = sqrtf(m);
    }
}

// == init: cov from partials, Y0 = cov/m (bf16), Z1 = 1.5I - 0.5*Y0 (bf16) ==
__global__ __launch_bounds__(256) void init_kernel(const short* __restrict__ Gp,
                                                   const float* __restrict__ S,
                                                   const float* __restrict__ mArr,
                                                   short* __restrict__ Y0,
                                                   short* __restrict__ Z1) {
    int idx = blockIdx.x * 256 + threadIdx.x;
    size_t e0 = (size_t)idx * 8;                // 8 elems / thread (16B)
    int b = (int)(e0 >> 16);
    int ij = (int)(e0 & 65535);
    int i = ij >> 8, j0 = ij & 255;
    float g[8] = {};
    #pragma unroll
    for (int sl = 0; sl < KS; ++sl) {
        bf16x8 t = *(const bf16x8*)(Gp + (size_t)sl * TOTE + e0);
        #pragma unroll
        for (int q = 0; q < 8; ++q) g[q] += bf2f(t[q]);
    }
    float Si = S[b * C_ + i];
    f32x4 sjA = *(const f32x4*)(S + b * C_ + j0);
    f32x4 sjB = *(const f32x4*)(S + b * C_ + j0 + 4);
    float invm = mArr[64 + b];
    const float invN = 1.0f / (float)N_;
    const float invN1 = 1.0f / (float)(N_ - 1);
    bf16x8 y, z;
    #pragma unroll
    for (int q = 0; q < 8; ++q) {
        float sj = (q < 4) ? sjA[q] : sjB[q - 4];
        float cov = (g[q] - Si * sj * invN) * invN1;
        float a = cov * invm;
        y[q] = f2bf(a);
        z[q] = f2bf(((i == j0 + q) ? 1.5f : 0.0f) - 0.5f * a);
    }
    *(bf16x8*)(Y0 + e0) = y;
    *(bf16x8*)(Z1 + e0) = z;
}

// ================= NS GEMM (K=256 in 2 staged halves, 64 KB LDS) =============
// acc[i,j] = sum_k A[i,k]*B[j,k]  (all iterates symmetric -> NT form)
// EP: 0 = P bf16 (acc); 1 = YZ' bf16 (1.5*Base - 0.5*acc), optional dual;
//     2 = final: out[b, triu(i,j)] = sqrt(m)*(1.5*Base - 0.5*acc), upper tiles
template<int EP, bool DUAL>
__global__ __launch_bounds__(256) void ns_gemm(
        const short* A0, const short* B0, const short* Ba0, void* C0,
        const short* A1, const short* B1, const short* Ba1, void* C1,
        const float* __restrict__ mArr) {
    int nb = gridDim.x, per = nb >> 3;
    int bid = (blockIdx.x & 7) * per + (blockIdx.x >> 3);  // XCD swizzle
    const short *A = A0, *B = B0, *Ba = Ba0; void* C = C0;
    if (DUAL && bid >= (nb >> 1)) { bid -= nb >> 1; A = A1; B = B1; Ba = Ba1; C = C1; }
    int b, ti, tj;
    if constexpr (EP == 2) {
        b = bid / 3; int t = bid % 3;
        ti = (t == 2) ? 1 : 0; tj = (t == 0) ? 0 : 1;     // (0,0),(0,1),(1,1)
    } else {
        b = bid >> 2; int t = bid & 3;
        ti = t >> 1; tj = t & 1;
    }
    const short* Ap = A + (size_t)b * MATE + (size_t)ti * 128 * C_;
    const short* Bp = B + (size_t)b * MATE + (size_t)tj * 128 * C_;

    __shared__ short As[16384], Bs[16384];   // 32 KB each: [128 rows][128 k]

    int tid = threadIdx.x, lane = tid & 63, wid = tid >> 6;
    int wr = wid >> 1, wc = wid & 1;
    int lr = lane & 15, hi = lane >> 4;
    f32x4 acc[4][4] = {};

    for (int h = 0; h < 2; ++h) {
        // stage half h: linear LDS dest, inverse-swizzled source (rule #21)
        #pragma unroll
        for (int q = 0; q < 8; ++q) {
            int d = (q * 256 + tid) * 16;
            int row = d >> 8;
            int inner = (d & 255) ^ ((row & 7) << 4);
            gload_lds16((const char*)Ap + (size_t)row * 512 + h * 256 + inner,
                        (char*)As + d);
            gload_lds16((const char*)Bp + (size_t)row * 512 + h * 256 + inner,
                        (char*)Bs + d);
        }
        __syncthreads();
        #pragma unroll
        for (int ks = 0; ks < 4; ++ks) {
            bf16x8 af[4], bb[4];
            #pragma unroll
            for (int m = 0; m < 4; ++m) {
                int rowa = wr * 64 + m * 16 + lr;
                af[m] = *(const bf16x8*)((const char*)As + rowa * 256 +
                                         ((ks * 64 + hi * 16) ^ ((rowa & 7) << 4)));
                int rowb = wc * 64 + m * 16 + lr;
                bb[m] = *(const bf16x8*)((const char*)Bs + rowb * 256 +
                                         ((ks * 64 + hi * 16) ^ ((rowb & 7) << 4)));
            }
            #pragma unroll
            for (int m = 0; m < 4; ++m)
                #pragma unroll
                for (int n = 0; n < 4; ++n)
                    acc[m][n] = __builtin_amdgcn_mfma_f32_16x16x32_bf16(af[m], bb[n], acc[m][n], 0, 0, 0);
        }
        if (h == 0) __syncthreads();   // buffer reuse for half 1
    }

    int r0 = hi * 4;
    float sqm = (EP == 2) ? mArr[128 + b] : 0.f;
    #pragma unroll
    for (int m = 0; m < 4; ++m)
        #pragma unroll
        for (int n = 0; n < 4; ++n)
            #pragma unroll
            for (int r = 0; r < 4; ++r) {
                int i = ti * 128 + wr * 64 + m * 16 + r0 + r;
                int j = tj * 128 + wc * 64 + n * 16 + lr;
                size_t idx = (size_t)b * MATE + (size_t)i * C_ + j;
                float v = acc[m][n][r];
                if constexpr (EP == 0) {
                    ((short*)C)[idx] = f2bf(v);
                } else if constexpr (EP == 1) {
                    ((short*)C)[idx] = f2bf(1.5f * bf2f(Ba[idx]) - 0.5f * v);
                } else {
                    if (j >= i) {
                        size_t o = (size_t)b * TRI + (size_t)i * C_ - (size_t)(i * (i - 1)) / 2 + (j - i);
                        ((float*)C)[o] = sqm * (1.5f * bf2f(Ba[idx]) - 0.5f * v);
                    }
                }
            }
}

extern "C" void kernel_launch(void* const* d_in, const int* in_sizes, int n_in,
                              void* d_out, int out_size, void* d_ws, size_t ws_size,
                              hipStream_t stream) {
    const float* x = (const float*)d_in[0];
    float* out = (float*)d_out;

    float* mArr = (float*)d_ws;                    // 256 floats (m, 1/m, sqrt m)
    float* S    = mArr + 256;                      // 16384
    float* Sp   = S + 16384;                       // KS*B*C = 65536
    short* Gp   = (short*)(Sp + (size_t)KS * B_ * C_);   // KS*TOTE bf16 = 32MB
    short* bufs = Gp + (size_t)KS * TOTE;
    short* M0 = bufs;                              // 5 bf16 matrices, 8MB each
    short* M1 = bufs + TOTE;
    short* M2 = bufs + 2 * TOTE;
    short* M3 = bufs + 3 * TOTE;
    short* M4 = bufs + 4 * TOTE;

    // gram partials (bf16) + row-sum partials
    gram_cov<<<B_ * KS, 1024, 0, stream>>>(x, Gp, Sp);
    // per-batch trace -> m, 1/m, sqrt(m); total row sums
    trace_kernel<<<B_, 256, 0, stream>>>(Gp, Sp, S, mArr);
    // cov assembly: Y0 -> M0, Z1 = 1.5I - 0.5*Y0 -> M1
    init_kernel<<<(int)(TOTE / 8 / 256), 256, 0, stream>>>(Gp, S, mArr, M0, M1);

    // it1 (Z0=I): Y1 = 1.5*Y0 - 0.5*Y0*Y0 -> M2
    ns_gemm<1, false><<<256, 256, 0, stream>>>(M0, M0, M0, M2,
                                               nullptr, nullptr, nullptr, nullptr, nullptr);
    // it2: P1 = Z1*Y1 -> M3
    ns_gemm<0, false><<<256, 256, 0, stream>>>(M1, M2, nullptr, M3,
                                               nullptr, nullptr, nullptr, nullptr, nullptr);
    //      Y2 = 1.5Y1 - 0.5*Y1*P1 -> M4 || Z2 = 1.5Z1 - 0.5*P1*Z1 -> M0
    ns_gemm<1, true><<<512, 256, 0, stream>>>(M2, M3, M2, M4,
                                              M3, M1, M1, M0, nullptr);
    // it3: P2 = Z2*Y2 -> M2
    ns_gemm<0, false><<<256, 256, 0, stream>>>(M0, M4, nullptr, M2,
                                               nullptr, nullptr, nullptr, nullptr, nullptr);
    //      final: out = sqrt(m)*(1.5Y2 - 0.5*Y2*P2), triu-packed, upper tiles
    ns_gemm<2, false><<<B_ * 3, 256, 0, stream>>>(M4, M2, M4, out,
                                                  nullptr, nullptr, nullptr, nullptr, mArr);
}